// Round 1
// baseline (3298.399 us; speedup 1.0000x reference)
//
#include <hip/hip_runtime.h>
#include <math.h>

#define TT 512
#define VV 32000
#define NB 250          // blocks; 250*128 = 32000 columns
#define NTHR 512        // 8 waves
#define BCOLS 128
#define MAXIT 1000
#define CHK 50
#define LDS_BYTES 133952

typedef float f4 __attribute__((ext_vector_type(4)));
typedef _Float16 h8 __attribute__((ext_vector_type(8)));
typedef _Float16 h2 __attribute__((ext_vector_type(2)));

// ---- DPP wave reductions (row_shr chain + row_bcast) ----
template <int CTRL>
__device__ __forceinline__ float dpp_add(float x) {
  int y = __builtin_amdgcn_update_dpp(0, __builtin_bit_cast(int, x), CTRL, 0xF, 0xF, true);
  return x + __builtin_bit_cast(float, y);
}
__device__ __forceinline__ float red16(float x) {  // valid on lanes 15 mod 16
  x = dpp_add<0x111>(x); x = dpp_add<0x112>(x);
  x = dpp_add<0x114>(x); x = dpp_add<0x118>(x);
  return x;
}
__device__ __forceinline__ float red32(float x) {  // valid on lanes 31, 63
  x = red16(x); x = dpp_add<0x142>(x); return x;
}
__device__ __forceinline__ float red64(float x) {  // valid on lane 63
  x = red32(x); x = dpp_add<0x143>(x); return x;
}

__device__ __forceinline__ int fswz(int row) { return (row ^ (row >> 5)) & 15; }

// generation-free grid barrier: monotone counter, target = nbar * NB
__device__ __forceinline__ void gbar(unsigned* cnt, unsigned target) {
  __threadfence();
  __syncthreads();
  if (threadIdx.x == 0) {
    __hip_atomic_fetch_add(cnt, 1u, __ATOMIC_ACQ_REL, __HIP_MEMORY_SCOPE_AGENT);
    while (__hip_atomic_load(cnt, __ATOMIC_ACQUIRE, __HIP_MEMORY_SCOPE_AGENT) < target) {
      __builtin_amdgcn_s_sleep(1);
    }
  }
  __syncthreads();
}

extern "C" __global__ void __launch_bounds__(NTHR, 1)
sink_kernel(const float* __restrict__ cost, float* __restrict__ D,
            float* __restrict__ errb, unsigned* __restrict__ cnt,
            float* __restrict__ lossp) {
  extern __shared__ char smem[];
  h8*       tile8 = (h8*)smem;                       // 512 rows x 16 chunks (swizzled), 128 KB
  float*    uf    = (float*)(smem + 131072);         // 512 f32
  float*    vf    = (float*)(smem + 133120);         // 128 f32
  _Float16* vh    = (_Float16*)(smem + 133632);      // 128 f16
  h8*       vh8   = (h8*)vh;
  float*    wred  = (float*)(smem + 133888);         // 8 f32

  const int t  = threadIdx.x;
  const int b  = blockIdx.x;
  const int cB = t & 15;        // chunk (8 cols)   — row-wise map
  const int rB = t >> 4;        // row slice 0..31
  const int gA = t >> 5;        // chunk            — col-wise map
  const int sA = t & 31;        // 16-row slice 0..31

  const float* cb = cost + (size_t)b * BCOLS;

  // ---- load tile: K~ = fp16(exp(-20 c)) ----
  for (int i = 0; i < 16; ++i) {
    int row = rB + 32 * i;
    const float* p = cb + (size_t)row * VV + cB * 8;
    f4 x0 = *(const f4*)p;
    f4 x1 = *(const f4*)(p + 4);
    h8 kk;
#pragma unroll
    for (int e = 0; e < 4; ++e) kk[e]     = (_Float16)__expf(-20.f * x0[e]);
#pragma unroll
    for (int e = 0; e < 4; ++e) kk[4 + e] = (_Float16)__expf(-20.f * x1[e]);
    tile8[row * 16 + (cB ^ fswz(row))] = kk;
  }
  uf[t] = 1.0f;  // u_bar = T*u = 1
  __syncthreads();

  unsigned nbar = 0;
  const bool writerA = ((t & 31) == 31);

  for (int it = 0; it < MAXIT; ++it) {
    // ---- Phase A: column sums Sa_j = mean_t K~ * u_bar ----
    float acc[8];
#pragma unroll
    for (int e = 0; e < 8; ++e) acc[e] = 0.f;
    f4 u4[4];
#pragma unroll
    for (int k = 0; k < 4; ++k) u4[k] = ((const f4*)uf)[sA * 4 + k];
#pragma unroll
    for (int i = 0; i < 16; ++i) {
      int row = sA * 16 + i;
      h8 kk = tile8[row * 16 + (gA ^ fswz(row))];
      float uu = u4[i >> 2][i & 3];
#pragma unroll
      for (int e = 0; e < 8; ++e) acc[e] = fmaf((float)kk[e], uu, acc[e]);
    }
#pragma unroll
    for (int e = 0; e < 8; ++e) acc[e] = red32(acc[e]);

    // ---- convergence check every 50 iters (uses old v, new u) ----
    if (it > 0 && (it % CHK) == 0) {
      int ci = it / CHK - 1;
      if (writerA) {
        float el = 0.f;
#pragma unroll
        for (int e = 0; e < 8; ++e) {
          float sa = acc[e] * (1.f / TT);
          el += fabsf(vf[gA * 8 + e] * sa - 1.f);
        }
        atomicAdd(&errb[ci], el);
      }
      gbar(cnt, (++nbar) * NB);
      float ev = __hip_atomic_load(&errb[ci], __ATOMIC_RELAXED, __HIP_MEMORY_SCOPE_AGENT);
      if (ev < 0.005f * VV) break;  // uniform across all blocks
    }

    // ---- v_bar = 1/(Sa + 1e-16) ----
    if (writerA) {
#pragma unroll
      for (int e = 0; e < 8; ++e) {
        float sa = acc[e] * (1.f / TT);
        float nv = 1.f / (sa + 1e-16f);
        vf[gA * 8 + e] = nv;
        vh[gA * 8 + e] = (_Float16)nv;
      }
    }
    __syncthreads();

    // ---- Phase B: partial row sums, atomic into D[it%3] ----
    float* Dbuf = D + (it % 3) * TT;
    h8 vv = vh8[cB];
#pragma unroll
    for (int i = 0; i < 16; ++i) {
      int row = rB + 32 * i;
      h8 kk = tile8[row * 16 + (cB ^ fswz(row))];
      float rs = 0.f;
      rs = __builtin_amdgcn_fdot2(h2{kk[0], kk[1]}, h2{vv[0], vv[1]}, rs, false);
      rs = __builtin_amdgcn_fdot2(h2{kk[2], kk[3]}, h2{vv[2], vv[3]}, rs, false);
      rs = __builtin_amdgcn_fdot2(h2{kk[4], kk[5]}, h2{vv[4], vv[5]}, rs, false);
      rs = __builtin_amdgcn_fdot2(h2{kk[6], kk[7]}, h2{vv[6], vv[7]}, rs, false);
      rs = red16(rs);
      if ((t & 15) == 15) atomicAdd(&Dbuf[row], rs);
    }
    // zero the buffer for iteration it+1 (3-buffer rotation makes this race-free)
    {
      float* Dn = D + ((it + 1) % 3) * TT;
      if (t < 3) {
        int idx = b + NB * t;
        if (idx < TT) __hip_atomic_store(&Dn[idx], 0.f, __ATOMIC_RELAXED, __HIP_MEMORY_SCOPE_AGENT);
      }
    }
    gbar(cnt, (++nbar) * NB);
    // ---- u_bar = 1/(D/V + 1e-16) ----
    float dv = __hip_atomic_load(&Dbuf[t], __ATOMIC_RELAXED, __HIP_MEMORY_SCOPE_AGENT);
    uf[t] = 1.f / (dv * (1.f / VV) + 1e-16f);
    __syncthreads();
  }

  // ---- loss partial: sum u_bar * exp(-20c) * v_bar * c over own stripe ----
  float lacc = 0.f;
  for (int i = 0; i < 16; ++i) {
    int row = rB + 32 * i;
    const float* p = cb + (size_t)row * VV + cB * 8;
    f4 x0 = *(const f4*)p;
    f4 x1 = *(const f4*)(p + 4);
    float um = uf[row];
    float inner = 0.f;
#pragma unroll
    for (int e = 0; e < 4; ++e) inner = fmaf(vf[cB * 8 + e] * __expf(-20.f * x0[e]), x0[e], inner);
#pragma unroll
    for (int e = 0; e < 4; ++e) inner = fmaf(vf[cB * 8 + 4 + e] * __expf(-20.f * x1[e]), x1[e], inner);
    lacc = fmaf(um, inner, lacc);
  }
  lacc = red64(lacc);
  if ((t & 63) == 63) wred[t >> 6] = lacc;
  __syncthreads();
  if (t == 0) {
    float s = 0.f;
#pragma unroll
    for (int w = 0; w < 8; ++w) s += wred[w];
    lossp[b] = s;
  }
}

extern "C" __global__ void prep_kernel(float* D, float* errb, unsigned* cnt, float* out) {
  int gid = threadIdx.x + blockIdx.x * blockDim.x;
  if (gid < 3 * TT) D[gid] = 0.f;
  if (gid < 20) errb[gid] = 0.f;
  if (gid == 0) { *cnt = 0u; out[0] = 0.f; }
}

extern "C" __global__ void final_kernel(const float* __restrict__ lossp, float* __restrict__ out) {
  int t = threadIdx.x;  // 64 threads, one wave
  float s = 0.f;
  for (int i = t; i < NB; i += 64) s += lossp[i];
  s = red64(s);
  if (t == 63) out[0] = s * (100.0f / ((float)TT * (float)VV));
}

extern "C" void kernel_launch(void* const* d_in, const int* in_sizes, int n_in,
                              void* d_out, int out_size, void* d_ws, size_t ws_size,
                              hipStream_t stream) {
  const float* cost = (const float*)d_in[0];
  float* out = (float*)d_out;
  char* ws = (char*)d_ws;
  float*    D     = (float*)ws;            // 3*512 f32
  float*    errb  = (float*)(ws + 6144);   // 20 f32
  unsigned* cnt   = (unsigned*)(ws + 6272);
  float*    lossp = (float*)(ws + 6400);   // 250 f32

  prep_kernel<<<6, 256, 0, stream>>>(D, errb, cnt, out);

  (void)hipFuncSetAttribute((const void*)sink_kernel,
                            hipFuncAttributeMaxDynamicSharedMemorySize, LDS_BYTES);
  void* args[] = {(void*)&cost, (void*)&D, (void*)&errb, (void*)&cnt, (void*)&lossp};
  (void)hipLaunchCooperativeKernel((const void*)sink_kernel, dim3(NB), dim3(NTHR),
                                   args, LDS_BYTES, stream);

  final_kernel<<<1, 64, 0, stream>>>(lossp, out);
}

// Round 2
// 659.711 us; speedup vs baseline: 4.9998x; 4.9998x over previous
//
#include <hip/hip_runtime.h>
#include <math.h>

#define TT 512
#define VV 32000
#define NB 250          // blocks; 250*128 = 32000 columns
#define NTHR 512        // 8 waves
#define BCOLS 128
#define MAXIT 1000
#define CHK 50
#define NCHK (MAXIT / CHK)
#define LDS_BYTES 136576

typedef float f4 __attribute__((ext_vector_type(4)));
typedef _Float16 h8 __attribute__((ext_vector_type(8)));
typedef _Float16 h2 __attribute__((ext_vector_type(2)));
typedef unsigned long long u64;

// ---- DPP wave reductions ----
template <int CTRL>
__device__ __forceinline__ float dpp_add(float x) {
  int y = __builtin_amdgcn_update_dpp(0, __builtin_bit_cast(int, x), CTRL, 0xF, 0xF, true);
  return x + __builtin_bit_cast(float, y);
}
__device__ __forceinline__ float red16(float x) {  // valid on lanes 15 mod 16
  x = dpp_add<0x111>(x); x = dpp_add<0x112>(x);
  x = dpp_add<0x114>(x); x = dpp_add<0x118>(x);
  return x;
}
__device__ __forceinline__ float red32(float x) {  // valid on lanes 31, 63
  x = red16(x); x = dpp_add<0x142>(x); return x;
}
__device__ __forceinline__ float red64(float x) {  // valid on lane 63
  x = red32(x); x = dpp_add<0x143>(x); return x;
}

__device__ __forceinline__ int fswz(int row) { return (row ^ (row >> 5)) & 15; }

__device__ __forceinline__ u64 ald(const u64* p) {
  return __hip_atomic_load((const u64*)p, __ATOMIC_RELAXED, __HIP_MEMORY_SCOPE_AGENT);
}
__device__ __forceinline__ void ast(u64* p, u64 v) {
  __hip_atomic_store(p, v, __ATOMIC_RELAXED, __HIP_MEMORY_SCOPE_AGENT);
}

extern "C" __global__ void __launch_bounds__(NTHR, 1)
sink_kernel(const float* __restrict__ cost, u64* __restrict__ partial,
            u64* __restrict__ upair, float* __restrict__ errb,
            float* __restrict__ lossp) {
  extern __shared__ char smem[];
  h8*       tile8  = (h8*)smem;                      // 512 x 16 chunks (swizzled), 128 KB
  float*    uf     = (float*)(smem + 131072);        // 512 f32
  float*    u_prev = (float*)(smem + 133120);        // 512 f32
  float*    vf     = (float*)(smem + 135168);        // 128 f32
  float*    v_prev = (float*)(smem + 135680);        // 128 f32
  _Float16* vh     = (_Float16*)(smem + 136192);     // 128 f16
  h8*       vh8    = (h8*)vh;
  float*    errw   = (float*)(smem + 136448);        // 16 f32
  float*    wred   = (float*)(smem + 136512);        // 8 f32

  const int t  = threadIdx.x;
  const int b  = blockIdx.x;
  const int cB = t & 15;        // chunk (8 cols)   — row-wise map
  const int rB = t >> 4;        // row slice 0..31
  const int gA = t >> 5;        // chunk            — col-wise map
  const int sA = t & 31;        // 16-row slice 0..31

  const float* cb = cost + (size_t)b * BCOLS;

  // ---- load tile: K~ = fp16(exp(-20 c)) ----
  for (int i = 0; i < 16; ++i) {
    int row = rB + 32 * i;
    const float* p = cb + (size_t)row * VV + cB * 8;
    f4 x0 = *(const f4*)p;
    f4 x1 = *(const f4*)(p + 4);
    h8 kk;
#pragma unroll
    for (int e = 0; e < 4; ++e) kk[e]     = (_Float16)__expf(-20.f * x0[e]);
#pragma unroll
    for (int e = 0; e < 4; ++e) kk[4 + e] = (_Float16)__expf(-20.f * x1[e]);
    tile8[row * 16 + (cB ^ fswz(row))] = kk;
  }
  uf[t] = 1.0f;  // u_bar = T*u = 1
  __syncthreads();

  const bool writerA = ((t & 31) == 31);
  const int rlo = (b * TT) / NB, rhi = ((b + 1) * TT) / NB;  // owned rows
  const int wv = t >> 6, ln = t & 63;
  bool converged = false;

  for (int it = 0; it < MAXIT; ++it) {
    const bool chk = (it > 0) && (it % CHK == 0);
    const int ci = it / CHK - 1;
    const unsigned st = (unsigned)(it + 1);
    const u64 stamp = ((u64)st) << 32;

    // ---- Phase A: column sums Sa_j = mean_t K~ * u_bar ----
    float acc[8];
#pragma unroll
    for (int e = 0; e < 8; ++e) acc[e] = 0.f;
    f4 u4[4];
#pragma unroll
    for (int k = 0; k < 4; ++k) u4[k] = ((const f4*)uf)[sA * 4 + k];
#pragma unroll
    for (int i = 0; i < 16; ++i) {
      int row = sA * 16 + i;
      h8 kk = tile8[row * 16 + (gA ^ fswz(row))];
      float uu = u4[i >> 2][i & 3];
#pragma unroll
      for (int e = 0; e < 8; ++e) acc[e] = fmaf((float)kk[e], uu, acc[e]);
    }
#pragma unroll
    for (int e = 0; e < 8; ++e) acc[e] = red32(acc[e]);

    if (chk) u_prev[t] = uf[t];  // snapshot u_it (uf not rewritten until iter end)

    // ---- v_bar = 1/(Sa + 1e-16); err uses OLD v ----
    if (writerA) {
      float el = 0.f;
#pragma unroll
      for (int e = 0; e < 8; ++e) {
        float sa = acc[e] * (1.f / TT);
        float vo = vf[gA * 8 + e];
        if (chk) { el += fabsf(vo * sa - 1.f); v_prev[gA * 8 + e] = vo; }
        float nv = 1.f / (sa + 1e-16f);
        vf[gA * 8 + e] = nv;
        vh[gA * 8 + e] = (_Float16)nv;
      }
      if (chk) errw[gA] = el;
    }
    __syncthreads();
    if (chk) {
      if (t == 0) {
        float s = 0.f;
#pragma unroll
        for (int w = 0; w < 16; ++w) s += errw[w];
        __hip_atomic_fetch_add(&errb[ci], s, __ATOMIC_RELAXED, __HIP_MEMORY_SCOPE_AGENT);
      }
      __syncthreads();  // drains t0's vmcnt -> err add globally done before stamps
    }

    // ---- Phase B: per-block row sums, stamped publish ----
    h8 vv = vh8[cB];
#pragma unroll
    for (int i = 0; i < 16; ++i) {
      int row = rB + 32 * i;
      h8 kk = tile8[row * 16 + (cB ^ fswz(row))];
      float rs = 0.f;
      rs = __builtin_amdgcn_fdot2(h2{kk[0], kk[1]}, h2{vv[0], vv[1]}, rs, false);
      rs = __builtin_amdgcn_fdot2(h2{kk[2], kk[3]}, h2{vv[2], vv[3]}, rs, false);
      rs = __builtin_amdgcn_fdot2(h2{kk[4], kk[5]}, h2{vv[4], vv[5]}, rs, false);
      rs = __builtin_amdgcn_fdot2(h2{kk[6], kk[7]}, h2{vv[6], vv[7]}, rs, false);
      rs = red16(rs);
      if ((t & 15) == 15)
        ast(&partial[(size_t)b * TT + row], stamp | (u64)__builtin_bit_cast(unsigned, rs));
    }

    // ---- owner reduce: poll stamps (poll IS the reduce), publish u[row] ----
    if (wv < rhi - rlo) {
      int row = rlo + wv;
      float vals[4];
      for (;;) {
        bool done = true;
#pragma unroll
        for (int k = 0; k < 4; ++k) {
          int bb = ln + 64 * k;
          vals[k] = 0.f;
          if (bb < NB) {
            u64 pv = ald(&partial[(size_t)bb * TT + row]);
            done = done && ((unsigned)(pv >> 32) == st);
            vals[k] = __builtin_bit_cast(float, (unsigned)pv);
          }
        }
        if (__all(done)) break;
        __builtin_amdgcn_s_sleep(1);
      }
      float s = vals[0] + vals[1] + vals[2] + vals[3];
      s = red64(s);
      if (ln == 63) {
        float unew = 1.f / (s * (1.f / VV) + 1e-16f);
        ast(&upair[row], stamp | (u64)__builtin_bit_cast(unsigned, unew));
      }
    }

    // ---- u broadcast poll: every thread waits on its own row (fused barrier) ----
    {
      u64 pv;
      for (;;) {
        pv = ald(&upair[t]);
        if ((unsigned)(pv >> 32) == st) break;
        __builtin_amdgcn_s_sleep(1);
      }
      uf[t] = __builtin_bit_cast(float, (unsigned)pv);
    }
    __syncthreads();

    if (chk) {
      if (t == 0) wred[0] = __hip_atomic_load(&errb[ci], __ATOMIC_RELAXED, __HIP_MEMORY_SCOPE_AGENT);
      __syncthreads();
      if (wred[0] < 0.005f * VV) { converged = true; break; }
    }
  }

  if (converged) {  // restore the pre-check state (matches reference exit)
    uf[t] = u_prev[t];
    if (t < 128) vf[t] = v_prev[t];
    __syncthreads();
  }

  // ---- loss partial: sum u_bar * exp(-20c) * v_bar * c over own stripe ----
  float lacc = 0.f;
  for (int i = 0; i < 16; ++i) {
    int row = rB + 32 * i;
    const float* p = cb + (size_t)row * VV + cB * 8;
    f4 x0 = *(const f4*)p;
    f4 x1 = *(const f4*)(p + 4);
    float um = uf[row];
    float inner = 0.f;
#pragma unroll
    for (int e = 0; e < 4; ++e) inner = fmaf(vf[cB * 8 + e] * __expf(-20.f * x0[e]), x0[e], inner);
#pragma unroll
    for (int e = 0; e < 4; ++e) inner = fmaf(vf[cB * 8 + 4 + e] * __expf(-20.f * x1[e]), x1[e], inner);
    lacc = fmaf(um, inner, lacc);
  }
  lacc = red64(lacc);
  if ((t & 63) == 63) wred[t >> 6] = lacc;
  __syncthreads();
  if (t == 0) {
    float s = 0.f;
#pragma unroll
    for (int w = 0; w < 8; ++w) s += wred[w];
    lossp[b] = s;
  }
}

extern "C" __global__ void prep_kernel(u64* zbuf, int nz, float* errb, float* out) {
  int gid = threadIdx.x + blockIdx.x * 256;
  for (int i = gid; i < nz; i += gridDim.x * 256) zbuf[i] = 0ull;
  if (gid < NCHK) errb[gid] = 0.f;
  if (gid == 0) out[0] = 0.f;
}

extern "C" __global__ void final_kernel(const float* __restrict__ lossp, float* __restrict__ out) {
  int t = threadIdx.x;  // 64 threads, one wave
  float s = 0.f;
  for (int i = t; i < NB; i += 64) s += lossp[i];
  s = red64(s);
  if (t == 63) out[0] = s * (100.0f / ((float)TT * (float)VV));
}

extern "C" void kernel_launch(void* const* d_in, const int* in_sizes, int n_in,
                              void* d_out, int out_size, void* d_ws, size_t ws_size,
                              hipStream_t stream) {
  const float* cost = (const float*)d_in[0];
  float* out = (float*)d_out;
  char* ws = (char*)d_ws;
  // layout: partial[256*512] u64 | upair[512] u64 | errb[20] f32 | lossp[256] f32
  u64*   partial = (u64*)ws;                      // 1,048,576 B (use 250*512, pad)
  u64*   upair   = (u64*)(ws + 1048576);          // 4096 B
  float* errb    = (float*)(ws + 1052672);        // 80 B
  float* lossp   = (float*)(ws + 1052800);        // 1024 B

  const int nz = 250 * TT + TT;  // partial (250 used) + upair
  prep_kernel<<<512, 256, 0, stream>>>(partial, nz, errb, out);

  (void)hipFuncSetAttribute((const void*)sink_kernel,
                            hipFuncAttributeMaxDynamicSharedMemorySize, LDS_BYTES);
  void* args[] = {(void*)&cost, (void*)&partial, (void*)&upair, (void*)&errb, (void*)&lossp};
  (void)hipLaunchCooperativeKernel((const void*)sink_kernel, dim3(NB), dim3(NTHR),
                                   args, LDS_BYTES, stream);

  final_kernel<<<1, 64, 0, stream>>>(lossp, out);
}